// Round 1
// baseline (317.172 us; speedup 1.0000x reference)
//
#include <hip/hip_runtime.h>

// GLRU associative scan, chunked 3-pass formulation.
// B=4, T=4096, D=1024. x[b][t][3*1024]: [inp_raw | input_gate_raw | output_gate_raw].
// Recurrence: h_t = a_t*h_{t-1} + b_t, a_t = 1-sigmoid(xg), b_t = tanh(xi)*sigmoid(xg),
// h_{-1} = carry (equivalent to reference's scan_ins[0] += carry*f_0).
// y_t = tanh(h_t)*sigmoid(xo). Outputs: h_last (4096 floats) then y (16.7M floats).

#define B_SZ 4
#define T_LEN 4096
#define DH 1024
#define ROW4 (3 * DH / 4)      // 768 float4 per (b,t) row
#define CHUNKS 128
#define CLEN (T_LEN / CHUNKS)  // 32 timesteps per chunk

__device__ __forceinline__ float fsig(float v) {
    // sigmoid(v) = 1/(1+e^-v); v_exp_f32 + v_rcp_f32, plenty accurate for 2e-2 threshold
    return __builtin_amdgcn_rcpf(1.0f + __expf(-v));
}
__device__ __forceinline__ float ftanh(float v) {
    // tanh(v) = 1 - 2/(e^{2v}+1); saturates cleanly (no inf/inf NaN)
    return 1.0f - 2.0f * __builtin_amdgcn_rcpf(__expf(2.0f * v) + 1.0f);
}

// Pass 1: per-chunk aggregates (A = prod a_t, B = local scan with h_in = 0).
// One float4 lane per 4 d-channels; grid (CHUNKS, B).
__global__ __launch_bounds__(256) void glru_pass1(const float* __restrict__ x,
                                                  float4* __restrict__ Aag,
                                                  float4* __restrict__ Bag) {
    const int c = blockIdx.x;
    const int b = blockIdx.y;
    const int d4 = threadIdx.x;  // 0..255 -> d = 4*d4..4*d4+3
    const float4* base = (const float4*)x + (size_t)(b * T_LEN + c * CLEN) * ROW4;

    float4 A = make_float4(1.f, 1.f, 1.f, 1.f);
    float4 Bv = make_float4(0.f, 0.f, 0.f, 0.f);
    for (int t = 0; t < CLEN; ++t) {
        const float4 vi = base[(size_t)t * ROW4 + d4];        // inp raw
        const float4 vg = base[(size_t)t * ROW4 + 256 + d4];  // input-gate raw
        {
            float ig = fsig(vg.x); float a = 1.f - ig;
            A.x *= a; Bv.x = a * Bv.x + ftanh(vi.x) * ig;
        }
        {
            float ig = fsig(vg.y); float a = 1.f - ig;
            A.y *= a; Bv.y = a * Bv.y + ftanh(vi.y) * ig;
        }
        {
            float ig = fsig(vg.z); float a = 1.f - ig;
            A.z *= a; Bv.z = a * Bv.z + ftanh(vi.z) * ig;
        }
        {
            float ig = fsig(vg.w); float a = 1.f - ig;
            A.w *= a; Bv.w = a * Bv.w + ftanh(vi.w) * ig;
        }
    }
    const int o = (b * CHUNKS + c) * 256 + d4;
    Aag[o] = A;
    Bag[o] = Bv;
}

// Pass 2: serial scan across chunk aggregates per (b,d) chain.
// 4096 threads; also emits h_last (output 0).
__global__ __launch_bounds__(256) void glru_pass2(const float* __restrict__ Aag,
                                                  const float* __restrict__ Bag,
                                                  const float* __restrict__ carry,
                                                  float* __restrict__ hinit,
                                                  float* __restrict__ hlast) {
    const int idx = blockIdx.x * 256 + threadIdx.x;  // 0..4095
    const int b = idx >> 10;
    const int d = idx & 1023;
    float h = carry[idx];
    #pragma unroll 8
    for (int c = 0; c < CHUNKS; ++c) {
        const int o = (b * CHUNKS + c) * 1024 + d;
        hinit[o] = h;
        h = Aag[o] * h + Bag[o];
    }
    hlast[idx] = h;
}

// Pass 3: re-read x, run recurrence from h_init, write y.
__global__ __launch_bounds__(256) void glru_pass3(const float* __restrict__ x,
                                                  const float4* __restrict__ hinit,
                                                  float4* __restrict__ y) {
    const int c = blockIdx.x;
    const int b = blockIdx.y;
    const int d4 = threadIdx.x;
    const float4* base = (const float4*)x + (size_t)(b * T_LEN + c * CLEN) * ROW4;
    float4* yb = y + (size_t)(b * T_LEN + c * CLEN) * 256;

    float4 h = hinit[(b * CHUNKS + c) * 256 + d4];
    for (int t = 0; t < CLEN; ++t) {
        const float4 vi = base[(size_t)t * ROW4 + d4];
        const float4 vg = base[(size_t)t * ROW4 + 256 + d4];
        const float4 vo = base[(size_t)t * ROW4 + 512 + d4];
        float4 out;
        {
            float ig = fsig(vg.x); float a = 1.f - ig;
            h.x = a * h.x + ftanh(vi.x) * ig;
            out.x = ftanh(h.x) * fsig(vo.x);
        }
        {
            float ig = fsig(vg.y); float a = 1.f - ig;
            h.y = a * h.y + ftanh(vi.y) * ig;
            out.y = ftanh(h.y) * fsig(vo.y);
        }
        {
            float ig = fsig(vg.z); float a = 1.f - ig;
            h.z = a * h.z + ftanh(vi.z) * ig;
            out.z = ftanh(h.z) * fsig(vo.z);
        }
        {
            float ig = fsig(vg.w); float a = 1.f - ig;
            h.w = a * h.w + ftanh(vi.w) * ig;
            out.w = ftanh(h.w) * fsig(vo.w);
        }
        yb[(size_t)t * 256 + d4] = out;
    }
}

extern "C" void kernel_launch(void* const* d_in, const int* in_sizes, int n_in,
                              void* d_out, int out_size, void* d_ws, size_t ws_size,
                              hipStream_t stream) {
    const float* x = (const float*)d_in[0];      // (4, 4096, 3072) fp32
    const float* carry = (const float*)d_in[1];  // (4, 1024) fp32

    float* hlast = (float*)d_out;                      // output 0: (4,1024)
    float4* y = (float4*)((float*)d_out + B_SZ * DH);  // output 1: (4,4096,1024)

    // workspace: A, B aggregates + h_init per chunk = 3 * 4*128*1024 floats = 6 MB
    float* Aag = (float*)d_ws;
    float* Bag = Aag + (size_t)B_SZ * CHUNKS * DH;
    float* hinit = Bag + (size_t)B_SZ * CHUNKS * DH;

    glru_pass1<<<dim3(CHUNKS, B_SZ), 256, 0, stream>>>(x, (float4*)Aag, (float4*)Bag);
    glru_pass2<<<16, 256, 0, stream>>>(Aag, Bag, carry, hinit, hlast);
    glru_pass3<<<dim3(CHUNKS, B_SZ), 256, 0, stream>>>(x, (const float4*)hinit, y);
}